// Round 8
// baseline (182.931 us; speedup 1.0000x reference)
//
#include <hip/hip_runtime.h>
#include <hip/hip_bf16.h>

// Problem constants
#define N_ROWS   16384      // 8*2048
#define EMB_DIM  64
#define NUM_EMB  8192
#define TOP_K    10
#define PERP_W   0.01

// r25 = r24 resubmitted verbatim (r24 bench was an infra failure: "MI355X
// container failed twice" — kernel never measured; same flake as r21/r22).
// r24 theory: gemm has two comparable floors — VALU ~35-40 us and L2
// codebook traffic (2048 blocks x 512 KB = 1 GB ~= 29 us at 34.5 TB/s),
// poorly overlapped because the compiler sinks prefetches (r19). 32-row
// blocks halve L2 traffic and amortize loads over 2x MFMA work. Dual
// independent per-row-set top-12 lists (la = rows 0-15, lb = rows 16-31)
// keep the dual-chain ILP, drop the final recombine, and preserve the exact
// per-row top-12 structure -> cand32 byte-identical. keysh [32][193];
// grid (512, 2); phase-2 8 rows/wave. prep/finalize/scalars r18-exact.

// Output layout (all float32, concatenated in return order)
#define QST_OFF   0
#define LOSS_OFF  (N_ROWS * EMB_DIM)                 // 1048576
#define IDX_OFF   (LOSS_OFF + 1)                     // 1048577
#define MIND_OFF  (IDX_OFF + N_ROWS)                 // 1064961
#define PERP_OFF  (MIND_OFF + N_ROWS)                // 1081345

// ws layout (bytes)
#define WS_E2C    0                                  // 8192 f32 = 512-||e||^2/2 (32 KB)
#define WS_E2D    32768                              // 8192 f64   (64 KB)
#define WS_CBS    98304                              // swizzled bf16 codebook (1 MB)
#define WS_HIST   1146880                            // 8192 i32  (32 KB)
#define WS_LOSSP  1179648                            // 4096 f64  (32 KB)
#define WS_NVP    1212416                            // 4096 i32  (16 KB)
#define WS_C32    1228800                            // 16384*32 u16 (1 MB)

typedef short bf16x8 __attribute__((ext_vector_type(8)));
typedef float f32x4  __attribute__((ext_vector_type(4)));

__device__ __forceinline__ unsigned umx(unsigned a, unsigned b) {
    return __builtin_elementwise_max(a, b);
}
__device__ __forceinline__ unsigned umn(unsigned a, unsigned b) {
    return __builtin_elementwise_min(a, b);
}

__device__ __forceinline__ unsigned short f2bf(float f) {
    // round-to-nearest-even fp32 -> bf16 (inputs are finite gaussians)
    unsigned int u = __float_as_uint(f);
    unsigned int r = u + 0x7fffu + ((u >> 16) & 1u);
    return (unsigned short)(r >> 16);
}

// ---------------------------------------------------------------------------
// Kernel 0: prep — 4 threads per code (128 blocks): quad shuffle-reduce for
// ||e||^2 (fp32 + fp64), bf16 swizzled stores, zero histogram.
// ---------------------------------------------------------------------------
__global__ __launch_bounds__(256) void vq_prep(const float* __restrict__ cb,
                                               float* __restrict__ e2c,
                                               double* __restrict__ e2d,
                                               unsigned short* __restrict__ cbs,
                                               int* __restrict__ hist) {
    const int g  = blockIdx.x * 256 + threadIdx.x;   // 0..32767
    const int k  = g >> 2;                           // code 0..8191
    const int lq = g & 3;                            // dim quarter

    if (g < NUM_EMB) hist[g] = 0;

    const float4* rp = (const float4*)(cb + (size_t)k * EMB_DIM + lq * 16);
    float  s  = 0.0f;
    double sd = 0.0;
    unsigned pk[8];
#pragma unroll
    for (int i = 0; i < 4; ++i) {
        const float4 v = rp[i];
        s  += v.x * v.x + v.y * v.y + v.z * v.z + v.w * v.w;
        sd += (double)v.x * (double)v.x + (double)v.y * (double)v.y
            + (double)v.z * (double)v.z + (double)v.w * (double)v.w;
        pk[2 * i + 0] = (unsigned)f2bf(v.x) | ((unsigned)f2bf(v.y) << 16);
        pk[2 * i + 1] = (unsigned)f2bf(v.z) | ((unsigned)f2bf(v.w) << 16);
    }
    // quad reduce (xor 1,2 stays inside the quad)
    s  += __shfl_xor(s, 1);  s  += __shfl_xor(s, 2);
    sd += __shfl_xor(sd, 1); sd += __shfl_xor(sd, 2);
    if (lq == 0) { e2c[k] = 512.0f - 0.5f * s; e2d[k] = sd; }

    // swizzled store: this thread owns 2 of the code's 8 16B chunks
    const int tp = k >> 5, r32 = k & 31, rsub = r32 & 15;
    unsigned short* basep = cbs + ((size_t)tp << 11)
                          + ((unsigned)(r32 & 16) << 6)
                          + (rsub << 3);
    const int hi  = lq >> 1;          // 0 = lo half (dims 0..31), 1 = hi half
    const int q2s = (lq & 1) * 2;     // starting q2 within half
    uint4 c0, c1;
    c0.x = pk[0]; c0.y = pk[1]; c0.z = pk[2]; c0.w = pk[3];
    c1.x = pk[4]; c1.y = pk[5]; c1.z = pk[6]; c1.w = pk[7];
    *(uint4*)(basep + hi * 512 + (q2s + 0) * 128) = c0;
    *(uint4*)(basep + hi * 512 + (q2s + 1) * 128) = c1;
}

// ---------------------------------------------------------------------------
// Kernel 1: MFMA distance GEMM + per-lane register top-12 (one list per
// row-set, two independent chains) + per-half per-row key-top-16 via ballot
// binary search. 32 rows x 4096 codes per block; grid (512, 2).
// ---------------------------------------------------------------------------
__global__ __launch_bounds__(256) void vq_gemm_topk(
        const float* __restrict__ inp, const unsigned short* __restrict__ cbs,
        const float* __restrict__ e2c, unsigned short* __restrict__ cand32) {
    __shared__ unsigned keysh[32][193];   // [row][slot 0..191], pad 193

    const int tid   = threadIdx.x;
    const int w     = tid >> 6;        // wave chunk 0..3
    const int lane  = tid & 63;
    const int q     = lane >> 4;       // quad: k-slice for A/B, code subgroup for D
    const int rsub  = lane & 15;
    const int row0  = blockIdx.x * 32;
    const int rowA  = row0 + rsub;         // row-set 0
    const int rowB  = row0 + 16 + rsub;    // row-set 1
    const int half0 = blockIdx.y * 4096;
    const int cbase = half0 + w * 1024;
    const int tpbase = cbase >> 5;     // tile-pair base index

    const int eoff = q << 2;           // e2 lane offset (floats)

    // B fragments for both row-sets (k = q*8+j and +32), fp32 -> bf16
    bf16x8 b0, b1, b2, b3;
    {
        const float* xpA = inp + (size_t)rowA * EMB_DIM + q * 8;
        const float* xpB = inp + (size_t)rowB * EMB_DIM + q * 8;
#pragma unroll
        for (int j = 0; j < 8; ++j) b0[j] = (short)f2bf(xpA[j]);
#pragma unroll
        for (int j = 0; j < 8; ++j) b1[j] = (short)f2bf(xpA[32 + j]);
#pragma unroll
        for (int j = 0; j < 8; ++j) b2[j] = (short)f2bf(xpB[j]);
#pragma unroll
        for (int j = 0; j < 8; ++j) b3[j] = (short)f2bf(xpB[32 + j]);
    }

    // independent sorted-desc top-12 lists: la <- row-set 0, lb <- row-set 1
    unsigned la[12], lb[12];
#pragma unroll
    for (int i = 0; i < 12; ++i) { la[i] = 0u; lb[i] = 0u; }

    // fully-coalesced loads: base is wave-uniform, lane offset = lane*16B
#define LOADP(P0,P1,P2,P3,E0,E1,TT) { \
        const bf16x8* bp_ = ((const bf16x8*)cbs) + (size_t)(tpbase + (TT)) * 256; \
        P0 = bp_[lane];        P1 = bp_[lane + 64]; \
        P2 = bp_[lane + 128];  P3 = bp_[lane + 192]; \
        const float* ep_ = e2c + cbase + (TT) * 32; \
        E0 = *(const f32x4*)(ep_ + eoff); \
        E1 = *(const f32x4*)(ep_ + eoff + 16); }

    bf16x8 A00, A01, A10, A11, B00, B01, B10, B11;
    f32x4  Ae0, Ae1, Be0, Be1;
    LOADP(A00, A01, A10, A11, Ae0, Ae1, 0)
    LOADP(B00, B01, B10, B11, Be0, Be1, 1)

    // descending compare-exchange: max to first operand
#define CE(A,B) { const unsigned mx_ = umx(A, B), mn_ = umn(A, B); \
                  A = mx_; B = mn_; }

    // descending 3-sort via 3-input ops (3 instrs, depth 1)
#define SORT3(A,B,C) { const unsigned x3_ = A, y3_ = B, z3_ = C; \
        unsigned mx3_, md3_, mn3_; \
        asm("v_max3_u32 %0, %1, %2, %3" : "=v"(mx3_) : "v"(x3_), "v"(y3_), "v"(z3_)); \
        asm("v_med3_u32 %0, %1, %2, %3" : "=v"(md3_) : "v"(x3_), "v"(y3_), "v"(z3_)); \
        asm("v_min3_u32 %0, %1, %2, %3" : "=v"(mn3_) : "v"(x3_), "v"(y3_), "v"(z3_)); \
        A = mx3_; B = md3_; C = mn3_; }

    // bitonic-12 cleaner, descending (valid for any bitonic-12 input)
#define RESORT(L) { \
        CE(L[0],L[6]) CE(L[1],L[7]) CE(L[2],L[8])  CE(L[3],L[9])  CE(L[4],L[10]) CE(L[5],L[11]) \
        CE(L[0],L[3]) CE(L[1],L[4]) CE(L[2],L[5])  CE(L[6],L[9])  CE(L[7],L[10]) CE(L[8],L[11]) \
        SORT3(L[0],L[1],L[2]) SORT3(L[3],L[4],L[5]) \
        SORT3(L[6],L[7],L[8]) SORT3(L[9],L[10],L[11]) }

    // Batcher odd-even mergesort, 8 keys, descending (19 CE)
#define SORT8(k0,k1,k2,k3,k4,k5,k6,k7) \
        CE(k0,k1) CE(k2,k3) CE(k4,k5) CE(k6,k7) \
        CE(k0,k2) CE(k1,k3) CE(k4,k6) CE(k5,k7) \
        CE(k1,k2) CE(k5,k6) \
        CE(k0,k4) CE(k1,k5) CE(k2,k6) CE(k3,k7) \
        CE(k2,k4) CE(k3,k5) \
        CE(k1,k2) CE(k3,k4) CE(k5,k6)

    // merge sorted-8 into sorted-12 list (half-cleaner pairing + resort)
#define MERGE12(L,k0,k1,k2,k3,k4,k5,k6,k7) \
        CE(L[11],k0) CE(L[10],k1) CE(L[9],k2) CE(L[8],k3) \
        CE(L[7],k4)  CE(L[6],k5)  CE(L[5],k6) CE(L[4],k7) \
        RESORT(L)

#define SUBITER(P0,P1,P2,P3,E0,E1,TT,TP) { \
        const bf16x8 c00_ = P0, c01_ = P1, c10_ = P2, c11_ = P3; \
        const f32x4  ce0_ = E0, ce1_ = E1; \
        LOADP(P0, P1, P2, P3, E0, E1, (TP) & 31) \
        f32x4 acc0_ = __builtin_amdgcn_mfma_f32_16x16x32_bf16(c00_, b0, ce0_, 0, 0, 0); \
        acc0_       = __builtin_amdgcn_mfma_f32_16x16x32_bf16(c01_, b1, acc0_, 0, 0, 0); \
        f32x4 acc1_ = __builtin_amdgcn_mfma_f32_16x16x32_bf16(c10_, b0, ce1_, 0, 0, 0); \
        acc1_       = __builtin_amdgcn_mfma_f32_16x16x32_bf16(c11_, b1, acc1_, 0, 0, 0); \
        f32x4 acc2_ = __builtin_amdgcn_mfma_f32_16x16x32_bf16(c00_, b2, ce0_, 0, 0, 0); \
        acc2_       = __builtin_amdgcn_mfma_f32_16x16x32_bf16(c01_, b3, acc2_, 0, 0, 0); \
        f32x4 acc3_ = __builtin_amdgcn_mfma_f32_16x16x32_bf16(c10_, b2, ce1_, 0, 0, 0); \
        acc3_       = __builtin_amdgcn_mfma_f32_16x16x32_bf16(c11_, b3, acc3_, 0, 0, 0); \
        const unsigned tb_ = (unsigned)((TT) << 3); \
        unsigned k0 = (__float_as_uint(acc0_[0]) & 0xFFFFFF00u) | (tb_ + 0u); \
        unsigned k1 = (__float_as_uint(acc0_[1]) & 0xFFFFFF00u) | (tb_ + 1u); \
        unsigned k2 = (__float_as_uint(acc0_[2]) & 0xFFFFFF00u) | (tb_ + 2u); \
        unsigned k3 = (__float_as_uint(acc0_[3]) & 0xFFFFFF00u) | (tb_ + 3u); \
        unsigned k4 = (__float_as_uint(acc1_[0]) & 0xFFFFFF00u) | (tb_ + 4u); \
        unsigned k5 = (__float_as_uint(acc1_[1]) & 0xFFFFFF00u) | (tb_ + 5u); \
        unsigned k6 = (__float_as_uint(acc1_[2]) & 0xFFFFFF00u) | (tb_ + 6u); \
        unsigned k7 = (__float_as_uint(acc1_[3]) & 0xFFFFFF00u) | (tb_ + 7u); \
        unsigned m0 = (__float_as_uint(acc2_[0]) & 0xFFFFFF00u) | (tb_ + 0u); \
        unsigned m1 = (__float_as_uint(acc2_[1]) & 0xFFFFFF00u) | (tb_ + 1u); \
        unsigned m2 = (__float_as_uint(acc2_[2]) & 0xFFFFFF00u) | (tb_ + 2u); \
        unsigned m3 = (__float_as_uint(acc2_[3]) & 0xFFFFFF00u) | (tb_ + 3u); \
        unsigned m4 = (__float_as_uint(acc3_[0]) & 0xFFFFFF00u) | (tb_ + 4u); \
        unsigned m5 = (__float_as_uint(acc3_[1]) & 0xFFFFFF00u) | (tb_ + 5u); \
        unsigned m6 = (__float_as_uint(acc3_[2]) & 0xFFFFFF00u) | (tb_ + 6u); \
        unsigned m7 = (__float_as_uint(acc3_[3]) & 0xFFFFFF00u) | (tb_ + 7u); \
        SORT8(k0,k1,k2,k3,k4,k5,k6,k7) \
        SORT8(m0,m1,m2,m3,m4,m5,m6,m7) \
        MERGE12(la, k0,k1,k2,k3,k4,k5,k6,k7) \
        MERGE12(lb, m0,m1,m2,m3,m4,m5,m6,m7) }

    for (int t = 0; t < 32; t += 2) {
        SUBITER(A00, A01, A10, A11, Ae0, Ae1, t,     t + 2)
        SUBITER(B00, B01, B10, B11, Be0, Be1, t + 1, t + 3)
    }
#undef SUBITER
#undef MERGE12
#undef SORT8
#undef RESORT
#undef SORT3
#undef CE
#undef LOADP

    // dump keys to LDS: slot = w*48 + q*12 + k  (0..191), rows rsub / rsub+16
    {
        unsigned* kr0 = &keysh[rsub][w * 48 + q * 12];
        unsigned* kr1 = &keysh[rsub + 16][w * 48 + q * 12];
#pragma unroll
        for (int i = 0; i < 12; ++i) kr0[i] = la[i];
#pragma unroll
        for (int i = 0; i < 12; ++i) kr1[i] = lb[i];
    }
    __syncthreads();

    // per-row key-top-16 over 192 keys via ballot binary search (8 rows/wave).
    for (int rr = 0; rr < 8; ++rr) {
        const int lr = 8 * w + rr;
        const unsigned ka = keysh[lr][lane];
        const unsigned kb = keysh[lr][lane + 64];
        const unsigned kc = keysh[lr][lane + 128];

        unsigned tau = 0u;
#pragma unroll
        for (int b = 31; b >= 0; --b) {
            const unsigned t2 = tau | (1u << b);
            const int cnt = __popcll(__ballot(ka >= t2))
                          + __popcll(__ballot(kb >= t2))
                          + __popcll(__ballot(kc >= t2));
            if (cnt >= 16) tau = t2;
        }

        const unsigned long long m0 = __ballot(ka >= tau);
        const unsigned long long m1 = __ballot(kb >= tau);
        const unsigned long long m2 = __ballot(kc >= tau);
        const unsigned long long below = (lane == 0) ? 0ull
                                        : (~0ull >> (64 - lane));
        const int c0 = __popcll(m0);
        const int c1 = __popcll(m1);
        const int p0 = __popcll(m0 & below);
        const int p1 = c0 + __popcll(m1 & below);
        const int p2 = c0 + c1 + __popcll(m2 & below);

        unsigned short* outp =
            cand32 + (size_t)(row0 + lr) * 32 + blockIdx.y * 16;

#define EMIT(KX, SLOT, POS) \
        if ((KX) >= tau && (POS) < 16) { \
            const unsigned slot_ = (unsigned)(SLOT); \
            const unsigned idx_  = (KX) & 0xFFu; \
            const unsigned wq_   = slot_ / 48u; \
            const unsigned qq_   = (slot_ % 48u) / 12u; \
            const unsigned code_ = (unsigned)half0 + wq_ * 1024u \
                                 + ((idx_ >> 3) << 5) + (((idx_ >> 2) & 1u) << 4) \
                                 + (qq_ << 2) + (idx_ & 3u); \
            outp[POS] = (unsigned short)code_; \
        }
        EMIT(ka, lane,       p0)
        EMIT(kb, lane + 64,  p1)
        EMIT(kc, lane + 128, p2)
#undef EMIT
    }
}

// ---------------------------------------------------------------------------
// Kernel 2: fp64 re-rank of the 32 candidates (both gathers + e2d hoisted,
// one latency exposure), rank-based stable (d,idx) selection + Gumbel argmax,
// outputs, scattered-bin histogram atomics, per-block partial stores.
// ---------------------------------------------------------------------------
__global__ __launch_bounds__(256) void vq_finalize(const float* __restrict__ inp,
                                                   const float* __restrict__ cb,
                                                   const double* __restrict__ e2d,
                                                   const float* __restrict__ gumbel,
                                                   const unsigned short* __restrict__ cand32,
                                                   float* __restrict__ out,
                                                   int* __restrict__ hist,
                                                   double* __restrict__ lossp,
                                                   int* __restrict__ nvp) {
    __shared__ double dvs[4][32];
    __shared__ int    dis[4][32];
    __shared__ double wl[4];
    __shared__ int    wv[4];

    const int tid  = threadIdx.x;
    const int w    = tid >> 6;
    const int lane = tid & 63;
    const int row  = blockIdx.x * 4 + w;
    const int g    = lane >> 2;   // quad id 0..15
    const int lq   = lane & 3;    // quarter within quad

    const float xf = inp[(size_t)row * EMB_DIM + lane];
    const double xd = (double)xf;

    // hoisted candidate ids + gathers + e2d (one latency exposure)
    const int code0 = (int)cand32[(size_t)row * 32 + g];
    const int code1 = (int)cand32[(size_t)row * 32 + 16 + g];
    const float4* ep0 = (const float4*)(cb + ((size_t)code0 << 6) + (lq << 4));
    const float4* ep1 = (const float4*)(cb + ((size_t)code1 << 6) + (lq << 4));
    const float4 a0 = ep0[0], a1 = ep0[1], a2 = ep0[2], a3 = ep0[3];
    const float4 b0 = ep1[0], b1 = ep1[1], b2 = ep1[2], b3 = ep1[3];
    const double ed0 = e2d[code0];
    const double ed1 = e2d[code1];

    // wave-wide ||x||^2 in fp64
    double x2 = xd * xd;
#pragma unroll
    for (int off = 32; off >= 1; off >>= 1) x2 += __shfl_xor(x2, off);
    const bool valid = sqrt(x2) > 1e-6;

    // lane's fp64 x-slice: dims [lq*16, lq*16+16) in registers
    double xq[16];
    {
        const float4* xp = (const float4*)(inp + (size_t)row * EMB_DIM + (lq << 4));
#pragma unroll
        for (int i = 0; i < 4; ++i) {
            const float4 v = xp[i];
            xq[4 * i + 0] = (double)v.x; xq[4 * i + 1] = (double)v.y;
            xq[4 * i + 2] = (double)v.z; xq[4 * i + 3] = (double)v.w;
        }
    }

#define DOT16(V0,V1,V2,V3, EDV, J, CODE) { \
        double d0_ = 0.0, d1_ = 0.0; \
        d0_ = fma(xq[0],  (double)V0.x, d0_);  d0_ = fma(xq[1],  (double)V0.y, d0_); \
        d0_ = fma(xq[2],  (double)V0.z, d0_);  d0_ = fma(xq[3],  (double)V0.w, d0_); \
        d0_ = fma(xq[4],  (double)V1.x, d0_);  d0_ = fma(xq[5],  (double)V1.y, d0_); \
        d0_ = fma(xq[6],  (double)V1.z, d0_);  d0_ = fma(xq[7],  (double)V1.w, d0_); \
        d1_ = fma(xq[8],  (double)V2.x, d1_);  d1_ = fma(xq[9],  (double)V2.y, d1_); \
        d1_ = fma(xq[10], (double)V2.z, d1_);  d1_ = fma(xq[11], (double)V2.w, d1_); \
        d1_ = fma(xq[12], (double)V3.x, d1_);  d1_ = fma(xq[13], (double)V3.y, d1_); \
        d1_ = fma(xq[14], (double)V3.z, d1_);  d1_ = fma(xq[15], (double)V3.w, d1_); \
        double dot_ = d0_ + d1_; \
        dot_ += __shfl_xor(dot_, 1); \
        dot_ += __shfl_xor(dot_, 2); \
        if (lq == 0) { \
            dvs[w][J] = x2 + (EDV) - 2.0 * dot_; \
            dis[w][J] = (CODE); \
        } }

    DOT16(a0, a1, a2, a3, ed0, g,      code0)
    DOT16(b0, b1, b2, b3, ed1, 16 + g, code1)
#undef DOT16
    __syncthreads();

    // one candidate per lane (lane<32). Rank by (d, idx) — exact stable order.
    const bool has = (lane < 32);
    double cd = has ? dvs[w][lane] : 1.0e300;
    int    ci = has ? dis[w][lane] : 0x7fffffff;

    int rank = 0;
#pragma unroll
    for (int off = 1; off < 32; ++off) {
        const double od = __shfl_xor(cd, off);   // stays within 0..31 group
        const int    oi = __shfl_xor(ci, off);
        if (od < cd || (od == cd && oi < ci)) ++rank;
    }

    // lanes with rank<10 (and holding a candidate) join the Gumbel race
    float sc = -3.0e38f;
    if (has && rank < TOP_K)
        sc = (float)(-cd) + gumbel[(size_t)row * TOP_K + rank];

    // wave argmax of (sc, tie -> smaller rank) carrying (cd, ci)
    double bd = cd; int bi = ci; int brk = rank;
#pragma unroll
    for (int off = 1; off < 64; off <<= 1) {
        const float  os = __shfl_xor(sc, off);
        const double od = __shfl_xor(bd, off);
        const int    oi = __shfl_xor(bi, off);
        const int    ork = __shfl_xor(brk, off);
        if (os > sc || (os == sc && ork < brk)) {
            sc = os; bd = od; bi = oi; brk = ork;
        }
    }
    const int   cidx = bi;            // uniform across wave
    const float mind = (float)bd;

    const float vm = valid ? 1.0f : 0.0f;
    const float qv = cb[(size_t)cidx * EMB_DIM + lane];
    out[QST_OFF + (size_t)row * EMB_DIM + lane] = xf + (qv * vm - xf);

    // loss term uses UNMASKED q_valid, masked by vm
    const double dq = (double)qv - xd;
    double l = dq * dq * (double)vm;
#pragma unroll
    for (int off = 32; off >= 1; off >>= 1) l += __shfl_xor(l, off);

    if (lane == 0) {
        wl[w] = l;
        wv[w] = valid ? 1 : 0;
        if (valid) atomicAdd(&hist[cidx], 1);   // scattered bins, low contention
        out[IDX_OFF + row]  = valid ? (float)cidx : 0.0f;
        out[MIND_OFF + row] = valid ? mind : 0.0f;
    }
    __syncthreads();
    if (tid == 0) {
        lossp[blockIdx.x] = wl[0] + wl[1] + wl[2] + wl[3];
        nvp[blockIdx.x]   = wv[0] + wv[1] + wv[2] + wv[3];
    }
}

// ---------------------------------------------------------------------------
// Kernel 3: reduce per-block partials + histogram entropy -> scalars.
// Single block, 1024 threads (16 waves).
// ---------------------------------------------------------------------------
__global__ __launch_bounds__(1024) void vq_scalars(const double* __restrict__ lossp,
                                                   const int* __restrict__ nvp,
                                                   const int* __restrict__ hist,
                                                   float* __restrict__ out) {
    __shared__ double red[1024];
    __shared__ double s_nv;
    const int tid = threadIdx.x;

    double lsum = 0.0;
    int    nvl  = 0;
#pragma unroll
    for (int i = 0; i < 4; ++i) {
        const int j = tid + 1024 * i;   // 4096 partials
        lsum += lossp[j];
        nvl  += nvp[j];
    }

    red[tid] = lsum;
    __syncthreads();
    for (int s = 512; s >= 1; s >>= 1) {
        if (tid < s) red[tid] += red[tid + s];
        __syncthreads();
    }
    const double losstot = red[0];
    __syncthreads();

    red[tid] = (double)nvl;
    __syncthreads();
    for (int s = 512; s >= 1; s >>= 1) {
        if (tid < s) red[tid] += red[tid + s];
        __syncthreads();
    }
    if (tid == 0) s_nv = (red[0] > 0.5) ? red[0] : 1.0;
    __syncthreads();
    const double nv = s_nv;
    __syncthreads();

    double h = 0.0;
#pragma unroll
    for (int i = 0; i < 8; ++i) {
        const int k = tid + 1024 * i;   // 8192 bins
        const double p = (double)hist[k] / nv;
        h += p * log(p + 1e-10);
    }
    red[tid] = h;
    __syncthreads();
    for (int s = 512; s >= 1; s >>= 1) {
        if (tid < s) red[tid] += red[tid + s];
        __syncthreads();
    }
    if (tid == 0) {
        const double H = red[0];                 // sum p*log(p+1e-10)
        const double perp = exp(-H);
        const double ploss = -log(perp + 1e-10);
        const double lvq = losstot / (nv * (double)EMB_DIM);
        out[LOSS_OFF] = (float)(lvq + PERP_W * ploss);
        out[PERP_OFF] = (float)perp;
    }
}

// ---------------------------------------------------------------------------
extern "C" void kernel_launch(void* const* d_in, const int* in_sizes, int n_in,
                              void* d_out, int out_size, void* d_ws, size_t ws_size,
                              hipStream_t stream) {
    const float* inp    = (const float*)d_in[0];  // [16384, 64]
    const float* cb     = (const float*)d_in[1];  // [8192, 64]
    const float* gumbel = (const float*)d_in[2];  // [16384, 10]
    float* out = (float*)d_out;

    char* ws = (char*)d_ws;
    float*          e2c    = (float*)(ws + WS_E2C);
    double*         e2d    = (double*)(ws + WS_E2D);
    unsigned short* cbs    = (unsigned short*)(ws + WS_CBS);
    int*            hist   = (int*)(ws + WS_HIST);
    double*         lossp  = (double*)(ws + WS_LOSSP);
    int*            nvp    = (int*)(ws + WS_NVP);
    unsigned short* cand32 = (unsigned short*)(ws + WS_C32);

    vq_prep<<<NUM_EMB * 4 / 256, 256, 0, stream>>>(cb, e2c, e2d, cbs, hist);
    vq_gemm_topk<<<dim3(N_ROWS / 32, 2), 256, 0, stream>>>(inp, cbs, e2c, cand32);
    vq_finalize<<<N_ROWS / 4, 256, 0, stream>>>(inp, cb, e2d, gumbel, cand32, out,
                                                hist, lossp, nvp);
    vq_scalars<<<1, 1024, 0, stream>>>(lossp, nvp, hist, out);
}

// Round 9
// 175.379 us; speedup vs baseline: 1.0431x; 1.0431x over previous
//
#include <hip/hip_runtime.h>
#include <hip/hip_bf16.h>

// Problem constants
#define N_ROWS   16384      // 8*2048
#define EMB_DIM  64
#define NUM_EMB  8192
#define TOP_K    10
#define PERP_W   0.01

// r26:
//  - gemm/prep/finalize: r18-exact (gemm 82.4 us measured; r19-r25 knobs and
//    the 32-row tile were all neutral-or-worse; L2 BW check: 1GB/84us = 12
//    TB/s = 35% of ceiling -> never the bottleneck).
//  - THE TAIL: vq_scalars did 8192 fp64 log() on ONE block (1 CU, 255 idle)
//    ~= 30-70 us hidden below gemm in top-5. Split: vq_entropy (8 blocks x
//    1024 thr, 1 bin/thread) computes partial sum p*log(p+1e-10); each block
//    integer-reduces nvp for nv (exact, order-free). Partials go in the
//    cand32 workspace (dead after finalize). vq_scalars keeps exact
//    lossp/nvp trees + sums 8 partials. Only H's fp64 summation grouping
//    changes (~1e-15 rel) -> invisible in fp32 outputs.

// Output layout (all float32, concatenated in return order)
#define QST_OFF   0
#define LOSS_OFF  (N_ROWS * EMB_DIM)                 // 1048576
#define IDX_OFF   (LOSS_OFF + 1)                     // 1048577
#define MIND_OFF  (IDX_OFF + N_ROWS)                 // 1064961
#define PERP_OFF  (MIND_OFF + N_ROWS)                // 1081345

// ws layout (bytes)
#define WS_E2C    0                                  // 8192 f32 = 512-||e||^2/2 (32 KB)
#define WS_E2D    32768                              // 8192 f64   (64 KB)
#define WS_CBS    98304                              // swizzled bf16 codebook (1 MB)
#define WS_HIST   1146880                            // 8192 i32  (32 KB)
#define WS_LOSSP  1179648                            // 4096 f64  (32 KB)
#define WS_NVP    1212416                            // 4096 i32  (16 KB)
#define WS_C32    1228800                            // 16384*32 u16 (1 MB); hpart reuses this after finalize

typedef short bf16x8 __attribute__((ext_vector_type(8)));
typedef float f32x4  __attribute__((ext_vector_type(4)));

__device__ __forceinline__ unsigned umx(unsigned a, unsigned b) {
    return __builtin_elementwise_max(a, b);
}
__device__ __forceinline__ unsigned umn(unsigned a, unsigned b) {
    return __builtin_elementwise_min(a, b);
}

__device__ __forceinline__ unsigned short f2bf(float f) {
    // round-to-nearest-even fp32 -> bf16 (inputs are finite gaussians)
    unsigned int u = __float_as_uint(f);
    unsigned int r = u + 0x7fffu + ((u >> 16) & 1u);
    return (unsigned short)(r >> 16);
}

// ---------------------------------------------------------------------------
// Kernel 0: prep — 4 threads per code (128 blocks): quad shuffle-reduce for
// ||e||^2 (fp32 + fp64), bf16 swizzled stores, zero histogram.
// ---------------------------------------------------------------------------
__global__ __launch_bounds__(256) void vq_prep(const float* __restrict__ cb,
                                               float* __restrict__ e2c,
                                               double* __restrict__ e2d,
                                               unsigned short* __restrict__ cbs,
                                               int* __restrict__ hist) {
    const int g  = blockIdx.x * 256 + threadIdx.x;   // 0..32767
    const int k  = g >> 2;                           // code 0..8191
    const int lq = g & 3;                            // dim quarter

    if (g < NUM_EMB) hist[g] = 0;

    const float4* rp = (const float4*)(cb + (size_t)k * EMB_DIM + lq * 16);
    float  s  = 0.0f;
    double sd = 0.0;
    unsigned pk[8];
#pragma unroll
    for (int i = 0; i < 4; ++i) {
        const float4 v = rp[i];
        s  += v.x * v.x + v.y * v.y + v.z * v.z + v.w * v.w;
        sd += (double)v.x * (double)v.x + (double)v.y * (double)v.y
            + (double)v.z * (double)v.z + (double)v.w * (double)v.w;
        pk[2 * i + 0] = (unsigned)f2bf(v.x) | ((unsigned)f2bf(v.y) << 16);
        pk[2 * i + 1] = (unsigned)f2bf(v.z) | ((unsigned)f2bf(v.w) << 16);
    }
    // quad reduce (xor 1,2 stays inside the quad)
    s  += __shfl_xor(s, 1);  s  += __shfl_xor(s, 2);
    sd += __shfl_xor(sd, 1); sd += __shfl_xor(sd, 2);
    if (lq == 0) { e2c[k] = 512.0f - 0.5f * s; e2d[k] = sd; }

    // swizzled store: this thread owns 2 of the code's 8 16B chunks
    const int tp = k >> 5, r32 = k & 31, rsub = r32 & 15;
    unsigned short* basep = cbs + ((size_t)tp << 11)
                          + ((unsigned)(r32 & 16) << 6)
                          + (rsub << 3);
    const int hi  = lq >> 1;          // 0 = lo half (dims 0..31), 1 = hi half
    const int q2s = (lq & 1) * 2;     // starting q2 within half
    uint4 c0, c1;
    c0.x = pk[0]; c0.y = pk[1]; c0.z = pk[2]; c0.w = pk[3];
    c1.x = pk[4]; c1.y = pk[5]; c1.z = pk[6]; c1.w = pk[7];
    *(uint4*)(basep + hi * 512 + (q2s + 0) * 128) = c0;
    *(uint4*)(basep + hi * 512 + (q2s + 1) * 128) = c1;
}

// ---------------------------------------------------------------------------
// Kernel 1: MFMA distance GEMM + per-lane register top-12 (dual-chain) +
// per-half per-row key-top-16 via ballot binary search. (r18-exact, 82.4 us)
// ---------------------------------------------------------------------------
__global__ __launch_bounds__(256) void vq_gemm_topk(
        const float* __restrict__ inp, const unsigned short* __restrict__ cbs,
        const float* __restrict__ e2c, unsigned short* __restrict__ cand32) {
    __shared__ unsigned keysh[16][193];   // [row][slot 0..191], pad 193

    const int tid   = threadIdx.x;
    const int w     = tid >> 6;        // wave chunk 0..3
    const int lane  = tid & 63;
    const int q     = lane >> 4;       // quad: k-slice for A/B, code subgroup for D
    const int rsub  = lane & 15;
    const int row0  = blockIdx.x * 16;
    const int row   = row0 + rsub;
    const int half0 = blockIdx.y * 4096;
    const int cbase = half0 + w * 1024;
    const int tpbase = cbase >> 5;     // tile-pair base index

    const int eoff = q << 2;           // e2 lane offset (floats)

    // B fragments (this lane's row, k = q*8+j and +32), fp32 -> bf16
    bf16x8 b0, b1;
    {
        const float* xp = inp + (size_t)row * EMB_DIM + q * 8;
#pragma unroll
        for (int j = 0; j < 8; ++j) b0[j] = (short)f2bf(xp[j]);
#pragma unroll
        for (int j = 0; j < 8; ++j) b1[j] = (short)f2bf(xp[32 + j]);
    }

    // two independent sorted-desc top-12 lists: la <- even tiles, lb <- odd
    unsigned la[12], lb[12];
#pragma unroll
    for (int i = 0; i < 12; ++i) { la[i] = 0u; lb[i] = 0u; }

    // fully-coalesced loads: base is wave-uniform, lane offset = lane*16B
#define LOADP(P0,P1,P2,P3,E0,E1,TT) { \
        const bf16x8* bp_ = ((const bf16x8*)cbs) + (size_t)(tpbase + (TT)) * 256; \
        P0 = bp_[lane];        P1 = bp_[lane + 64]; \
        P2 = bp_[lane + 128];  P3 = bp_[lane + 192]; \
        const float* ep_ = e2c + cbase + (TT) * 32; \
        E0 = *(const f32x4*)(ep_ + eoff); \
        E1 = *(const f32x4*)(ep_ + eoff + 16); }

    bf16x8 A00, A01, A10, A11, B00, B01, B10, B11;
    f32x4  Ae0, Ae1, Be0, Be1;
    LOADP(A00, A01, A10, A11, Ae0, Ae1, 0)
    LOADP(B00, B01, B10, B11, Be0, Be1, 1)

    // descending compare-exchange: max to first operand
#define CE(A,B) { const unsigned mx_ = umx(A, B), mn_ = umn(A, B); \
                  A = mx_; B = mn_; }

    // descending 3-sort via 3-input ops (3 instrs, depth 1)
#define SORT3(A,B,C) { const unsigned x3_ = A, y3_ = B, z3_ = C; \
        unsigned mx3_, md3_, mn3_; \
        asm("v_max3_u32 %0, %1, %2, %3" : "=v"(mx3_) : "v"(x3_), "v"(y3_), "v"(z3_)); \
        asm("v_med3_u32 %0, %1, %2, %3" : "=v"(md3_) : "v"(x3_), "v"(y3_), "v"(z3_)); \
        asm("v_min3_u32 %0, %1, %2, %3" : "=v"(mn3_) : "v"(x3_), "v"(y3_), "v"(z3_)); \
        A = mx3_; B = md3_; C = mn3_; }

    // bitonic-12 cleaner, descending (valid for any bitonic-12 input)
#define RESORT(L) { \
        CE(L[0],L[6]) CE(L[1],L[7]) CE(L[2],L[8])  CE(L[3],L[9])  CE(L[4],L[10]) CE(L[5],L[11]) \
        CE(L[0],L[3]) CE(L[1],L[4]) CE(L[2],L[5])  CE(L[6],L[9])  CE(L[7],L[10]) CE(L[8],L[11]) \
        SORT3(L[0],L[1],L[2]) SORT3(L[3],L[4],L[5]) \
        SORT3(L[6],L[7],L[8]) SORT3(L[9],L[10],L[11]) }

#define SUBITER(P0,P1,P2,P3,E0,E1,TT,TP,L) { \
        const bf16x8 c00_ = P0, c01_ = P1, c10_ = P2, c11_ = P3; \
        const f32x4  ce0_ = E0, ce1_ = E1; \
        LOADP(P0, P1, P2, P3, E0, E1, (TP) & 31) \
        f32x4 acc0_ = __builtin_amdgcn_mfma_f32_16x16x32_bf16(c00_, b0, ce0_, 0, 0, 0); \
        acc0_       = __builtin_amdgcn_mfma_f32_16x16x32_bf16(c01_, b1, acc0_, 0, 0, 0); \
        f32x4 acc1_ = __builtin_amdgcn_mfma_f32_16x16x32_bf16(c10_, b0, ce1_, 0, 0, 0); \
        acc1_       = __builtin_amdgcn_mfma_f32_16x16x32_bf16(c11_, b1, acc1_, 0, 0, 0); \
        const unsigned tb_ = (unsigned)((TT) << 3); \
        unsigned k0 = (__float_as_uint(acc0_[0]) & 0xFFFFFF00u) | (tb_ + 0u); \
        unsigned k1 = (__float_as_uint(acc0_[1]) & 0xFFFFFF00u) | (tb_ + 1u); \
        unsigned k2 = (__float_as_uint(acc0_[2]) & 0xFFFFFF00u) | (tb_ + 2u); \
        unsigned k3 = (__float_as_uint(acc0_[3]) & 0xFFFFFF00u) | (tb_ + 3u); \
        unsigned k4 = (__float_as_uint(acc1_[0]) & 0xFFFFFF00u) | (tb_ + 4u); \
        unsigned k5 = (__float_as_uint(acc1_[1]) & 0xFFFFFF00u) | (tb_ + 5u); \
        unsigned k6 = (__float_as_uint(acc1_[2]) & 0xFFFFFF00u) | (tb_ + 6u); \
        unsigned k7 = (__float_as_uint(acc1_[3]) & 0xFFFFFF00u) | (tb_ + 7u); \
        /* Batcher odd-even mergesort, 8 keys, descending (19 CE) */ \
        CE(k0,k1) CE(k2,k3) CE(k4,k5) CE(k6,k7) \
        CE(k0,k2) CE(k1,k3) CE(k4,k6) CE(k5,k7) \
        CE(k1,k2) CE(k5,k6) \
        CE(k0,k4) CE(k1,k5) CE(k2,k6) CE(k3,k7) \
        CE(k2,k4) CE(k3,k5) \
        CE(k1,k2) CE(k3,k4) CE(k5,k6) \
        /* unconditional half-cleaner merge (no-op when nothing inserts) */ \
        CE(L[11],k0) CE(L[10],k1) CE(L[9],k2) CE(L[8],k3) \
        CE(L[7],k4)  CE(L[6],k5)  CE(L[5],k6) CE(L[4],k7) \
        RESORT(L) }

    for (int t = 0; t < 32; t += 2) {
        SUBITER(A00, A01, A10, A11, Ae0, Ae1, t,     t + 2, la)
        SUBITER(B00, B01, B10, B11, Be0, Be1, t + 1, t + 3, lb)
    }
#undef SUBITER
#undef LOADP

    // recombine: top-12(la ∪ lb) sorted desc — identical multiset+order to a
    // single-list top-12 of all 256 keys.  12-wide half-cleaner, then resort.
    CE(la[11], lb[0]) CE(la[10], lb[1]) CE(la[9], lb[2])  CE(la[8], lb[3])
    CE(la[7],  lb[4]) CE(la[6],  lb[5]) CE(la[5], lb[6])  CE(la[4], lb[7])
    CE(la[3],  lb[8]) CE(la[2],  lb[9]) CE(la[1], lb[10]) CE(la[0], lb[11])
    RESORT(la)
#undef RESORT
#undef SORT3
#undef CE

    // dump keys to LDS: slot = w*48 + q*12 + k  (0..191)
    {
        unsigned* kr = &keysh[rsub][w * 48 + q * 12];
#pragma unroll
        for (int i = 0; i < 12; ++i) kr[i] = la[i];
    }
    __syncthreads();

    // per-row key-top-16 over 192 keys via ballot binary search.
    for (int rr = 0; rr < 4; ++rr) {
        const int lr = 4 * w + rr;
        const unsigned ka = keysh[lr][lane];
        const unsigned kb = keysh[lr][lane + 64];
        const unsigned kc = keysh[lr][lane + 128];

        unsigned tau = 0u;
#pragma unroll
        for (int b = 31; b >= 0; --b) {
            const unsigned t2 = tau | (1u << b);
            const int cnt = __popcll(__ballot(ka >= t2))
                          + __popcll(__ballot(kb >= t2))
                          + __popcll(__ballot(kc >= t2));
            if (cnt >= 16) tau = t2;
        }

        const unsigned long long m0 = __ballot(ka >= tau);
        const unsigned long long m1 = __ballot(kb >= tau);
        const unsigned long long m2 = __ballot(kc >= tau);
        const unsigned long long below = (lane == 0) ? 0ull
                                        : (~0ull >> (64 - lane));
        const int c0 = __popcll(m0);
        const int c1 = __popcll(m1);
        const int p0 = __popcll(m0 & below);
        const int p1 = c0 + __popcll(m1 & below);
        const int p2 = c0 + c1 + __popcll(m2 & below);

        unsigned short* outp =
            cand32 + (size_t)(row0 + lr) * 32 + blockIdx.y * 16;

#define EMIT(KX, SLOT, POS) \
        if ((KX) >= tau && (POS) < 16) { \
            const unsigned slot_ = (unsigned)(SLOT); \
            const unsigned idx_  = (KX) & 0xFFu; \
            const unsigned wq_   = slot_ / 48u; \
            const unsigned qq_   = (slot_ % 48u) / 12u; \
            const unsigned code_ = (unsigned)half0 + wq_ * 1024u \
                                 + ((idx_ >> 3) << 5) + (((idx_ >> 2) & 1u) << 4) \
                                 + (qq_ << 2) + (idx_ & 3u); \
            outp[POS] = (unsigned short)code_; \
        }
        EMIT(ka, lane,       p0)
        EMIT(kb, lane + 64,  p1)
        EMIT(kc, lane + 128, p2)
#undef EMIT
    }
}

// ---------------------------------------------------------------------------
// Kernel 2: fp64 re-rank of the 32 candidates (both gathers + e2d hoisted,
// one latency exposure), rank-based stable (d,idx) selection + Gumbel argmax,
// outputs, scattered-bin histogram atomics, per-block partial stores.
// ---------------------------------------------------------------------------
__global__ __launch_bounds__(256) void vq_finalize(const float* __restrict__ inp,
                                                   const float* __restrict__ cb,
                                                   const double* __restrict__ e2d,
                                                   const float* __restrict__ gumbel,
                                                   const unsigned short* __restrict__ cand32,
                                                   float* __restrict__ out,
                                                   int* __restrict__ hist,
                                                   double* __restrict__ lossp,
                                                   int* __restrict__ nvp) {
    __shared__ double dvs[4][32];
    __shared__ int    dis[4][32];
    __shared__ double wl[4];
    __shared__ int    wv[4];

    const int tid  = threadIdx.x;
    const int w    = tid >> 6;
    const int lane = tid & 63;
    const int row  = blockIdx.x * 4 + w;
    const int g    = lane >> 2;   // quad id 0..15
    const int lq   = lane & 3;    // quarter within quad

    const float xf = inp[(size_t)row * EMB_DIM + lane];
    const double xd = (double)xf;

    // hoisted candidate ids + gathers + e2d (one latency exposure)
    const int code0 = (int)cand32[(size_t)row * 32 + g];
    const int code1 = (int)cand32[(size_t)row * 32 + 16 + g];
    const float4* ep0 = (const float4*)(cb + ((size_t)code0 << 6) + (lq << 4));
    const float4* ep1 = (const float4*)(cb + ((size_t)code1 << 6) + (lq << 4));
    const float4 a0 = ep0[0], a1 = ep0[1], a2 = ep0[2], a3 = ep0[3];
    const float4 b0 = ep1[0], b1 = ep1[1], b2 = ep1[2], b3 = ep1[3];
    const double ed0 = e2d[code0];
    const double ed1 = e2d[code1];

    // wave-wide ||x||^2 in fp64
    double x2 = xd * xd;
#pragma unroll
    for (int off = 32; off >= 1; off >>= 1) x2 += __shfl_xor(x2, off);
    const bool valid = sqrt(x2) > 1e-6;

    // lane's fp64 x-slice: dims [lq*16, lq*16+16) in registers
    double xq[16];
    {
        const float4* xp = (const float4*)(inp + (size_t)row * EMB_DIM + (lq << 4));
#pragma unroll
        for (int i = 0; i < 4; ++i) {
            const float4 v = xp[i];
            xq[4 * i + 0] = (double)v.x; xq[4 * i + 1] = (double)v.y;
            xq[4 * i + 2] = (double)v.z; xq[4 * i + 3] = (double)v.w;
        }
    }

#define DOT16(V0,V1,V2,V3, EDV, J, CODE) { \
        double d0_ = 0.0, d1_ = 0.0; \
        d0_ = fma(xq[0],  (double)V0.x, d0_);  d0_ = fma(xq[1],  (double)V0.y, d0_); \
        d0_ = fma(xq[2],  (double)V0.z, d0_);  d0_ = fma(xq[3],  (double)V0.w, d0_); \
        d0_ = fma(xq[4],  (double)V1.x, d0_);  d0_ = fma(xq[5],  (double)V1.y, d0_); \
        d0_ = fma(xq[6],  (double)V1.z, d0_);  d0_ = fma(xq[7],  (double)V1.w, d0_); \
        d1_ = fma(xq[8],  (double)V2.x, d1_);  d1_ = fma(xq[9],  (double)V2.y, d1_); \
        d1_ = fma(xq[10], (double)V2.z, d1_);  d1_ = fma(xq[11], (double)V2.w, d1_); \
        d1_ = fma(xq[12], (double)V3.x, d1_);  d1_ = fma(xq[13], (double)V3.y, d1_); \
        d1_ = fma(xq[14], (double)V3.z, d1_);  d1_ = fma(xq[15], (double)V3.w, d1_); \
        double dot_ = d0_ + d1_; \
        dot_ += __shfl_xor(dot_, 1); \
        dot_ += __shfl_xor(dot_, 2); \
        if (lq == 0) { \
            dvs[w][J] = x2 + (EDV) - 2.0 * dot_; \
            dis[w][J] = (CODE); \
        } }

    DOT16(a0, a1, a2, a3, ed0, g,      code0)
    DOT16(b0, b1, b2, b3, ed1, 16 + g, code1)
#undef DOT16
    __syncthreads();

    // one candidate per lane (lane<32). Rank by (d, idx) — exact stable order.
    const bool has = (lane < 32);
    double cd = has ? dvs[w][lane] : 1.0e300;
    int    ci = has ? dis[w][lane] : 0x7fffffff;

    int rank = 0;
#pragma unroll
    for (int off = 1; off < 32; ++off) {
        const double od = __shfl_xor(cd, off);   // stays within 0..31 group
        const int    oi = __shfl_xor(ci, off);
        if (od < cd || (od == cd && oi < ci)) ++rank;
    }

    // lanes with rank<10 (and holding a candidate) join the Gumbel race
    float sc = -3.0e38f;
    if (has && rank < TOP_K)
        sc = (float)(-cd) + gumbel[(size_t)row * TOP_K + rank];

    // wave argmax of (sc, tie -> smaller rank) carrying (cd, ci)
    double bd = cd; int bi = ci; int brk = rank;
#pragma unroll
    for (int off = 1; off < 64; off <<= 1) {
        const float  os = __shfl_xor(sc, off);
        const double od = __shfl_xor(bd, off);
        const int    oi = __shfl_xor(bi, off);
        const int    ork = __shfl_xor(brk, off);
        if (os > sc || (os == sc && ork < brk)) {
            sc = os; bd = od; bi = oi; brk = ork;
        }
    }
    const int   cidx = bi;            // uniform across wave
    const float mind = (float)bd;

    const float vm = valid ? 1.0f : 0.0f;
    const float qv = cb[(size_t)cidx * EMB_DIM + lane];
    out[QST_OFF + (size_t)row * EMB_DIM + lane] = xf + (qv * vm - xf);

    // loss term uses UNMASKED q_valid, masked by vm
    const double dq = (double)qv - xd;
    double l = dq * dq * (double)vm;
#pragma unroll
    for (int off = 32; off >= 1; off >>= 1) l += __shfl_xor(l, off);

    if (lane == 0) {
        wl[w] = l;
        wv[w] = valid ? 1 : 0;
        if (valid) atomicAdd(&hist[cidx], 1);   // scattered bins, low contention
        out[IDX_OFF + row]  = valid ? (float)cidx : 0.0f;
        out[MIND_OFF + row] = valid ? mind : 0.0f;
    }
    __syncthreads();
    if (tid == 0) {
        lossp[blockIdx.x] = wl[0] + wl[1] + wl[2] + wl[3];
        nvp[blockIdx.x]   = wv[0] + wv[1] + wv[2] + wv[3];
    }
}

// ---------------------------------------------------------------------------
// Kernel 3a: entropy partials — 8 blocks x 1024 threads, one bin per thread.
// Each block integer-reduces nvp (order-free, exact) for nv, computes its
// 1024 bins' p*log(p+1e-10), tree-reduces, writes one double partial.
// Spreads the 8192 fp64 log() calls over 8 CUs instead of 1.
// ---------------------------------------------------------------------------
__global__ __launch_bounds__(1024) void vq_entropy(const int* __restrict__ nvp,
                                                   const int* __restrict__ hist,
                                                   double* __restrict__ hpart) {
    __shared__ int    redi[1024];
    __shared__ double red[1024];
    const int tid = threadIdx.x;

    // nv: integer sum of 4096 per-block valid counts (order-independent)
    int nvl = 0;
#pragma unroll
    for (int i = 0; i < 4; ++i) nvl += nvp[tid + 1024 * i];
    redi[tid] = nvl;
    __syncthreads();
    for (int s = 512; s >= 1; s >>= 1) {
        if (tid < s) redi[tid] += redi[tid + s];
        __syncthreads();
    }
    const double nv = (redi[0] > 0) ? (double)redi[0] : 1.0;

    // this thread's bin term
    const int k = blockIdx.x * 1024 + tid;
    const double p = (double)hist[k] / nv;
    red[tid] = p * log(p + 1e-10);
    __syncthreads();
    for (int s = 512; s >= 1; s >>= 1) {
        if (tid < s) red[tid] += red[tid + s];
        __syncthreads();
    }
    if (tid == 0) hpart[blockIdx.x] = red[0];
}

// ---------------------------------------------------------------------------
// Kernel 3b: reduce per-block partials -> scalars. Single block, 1024 threads.
// losstot and nv trees identical to the original; H = serial sum of the 8
// entropy partials.
// ---------------------------------------------------------------------------
__global__ __launch_bounds__(1024) void vq_scalars(const double* __restrict__ lossp,
                                                   const int* __restrict__ nvp,
                                                   const double* __restrict__ hpart,
                                                   float* __restrict__ out) {
    __shared__ double red[1024];
    __shared__ double s_nv;
    const int tid = threadIdx.x;

    double lsum = 0.0;
    int    nvl  = 0;
#pragma unroll
    for (int i = 0; i < 4; ++i) {
        const int j = tid + 1024 * i;   // 4096 partials
        lsum += lossp[j];
        nvl  += nvp[j];
    }

    red[tid] = lsum;
    __syncthreads();
    for (int s = 512; s >= 1; s >>= 1) {
        if (tid < s) red[tid] += red[tid + s];
        __syncthreads();
    }
    const double losstot = red[0];
    __syncthreads();

    red[tid] = (double)nvl;
    __syncthreads();
    for (int s = 512; s >= 1; s >>= 1) {
        if (tid < s) red[tid] += red[tid + s];
        __syncthreads();
    }
    if (tid == 0) s_nv = (red[0] > 0.5) ? red[0] : 1.0;
    __syncthreads();
    const double nv = s_nv;

    if (tid == 0) {
        double H = 0.0;
#pragma unroll
        for (int b = 0; b < 8; ++b) H += hpart[b];
        const double perp = exp(-H);
        const double ploss = -log(perp + 1e-10);
        const double lvq = losstot / (nv * (double)EMB_DIM);
        out[LOSS_OFF] = (float)(lvq + PERP_W * ploss);
        out[PERP_OFF] = (float)perp;
    }
}

// ---------------------------------------------------------------------------
extern "C" void kernel_launch(void* const* d_in, const int* in_sizes, int n_in,
                              void* d_out, int out_size, void* d_ws, size_t ws_size,
                              hipStream_t stream) {
    const float* inp    = (const float*)d_in[0];  // [16384, 64]
    const float* cb     = (const float*)d_in[1];  // [8192, 64]
    const float* gumbel = (const float*)d_in[2];  // [16384, 10]
    float* out = (float*)d_out;

    char* ws = (char*)d_ws;
    float*          e2c    = (float*)(ws + WS_E2C);
    double*         e2d    = (double*)(ws + WS_E2D);
    unsigned short* cbs    = (unsigned short*)(ws + WS_CBS);
    int*            hist   = (int*)(ws + WS_HIST);
    double*         lossp  = (double*)(ws + WS_LOSSP);
    int*            nvp    = (int*)(ws + WS_NVP);
    unsigned short* cand32 = (unsigned short*)(ws + WS_C32);
    double*         hpart  = (double*)(ws + WS_C32);  // reuses cand32 (dead after finalize)

    vq_prep<<<NUM_EMB * 4 / 256, 256, 0, stream>>>(cb, e2c, e2d, cbs, hist);
    vq_gemm_topk<<<dim3(N_ROWS / 16, 2), 256, 0, stream>>>(inp, cbs, e2c, cand32);
    vq_finalize<<<N_ROWS / 4, 256, 0, stream>>>(inp, cb, e2d, gumbel, cand32, out,
                                                hist, lossp, nvp);
    vq_entropy<<<8, 1024, 0, stream>>>(nvp, hist, hpart);
    vq_scalars<<<1, 1024, 0, stream>>>(lossp, nvp, hpart, out);
}

// Round 11
// 175.335 us; speedup vs baseline: 1.0433x; 1.0003x over previous
//
#include <hip/hip_runtime.h>
#include <hip/hip_bf16.h>

// Problem constants
#define N_ROWS   16384      // 8*2048
#define EMB_DIM  64
#define NUM_EMB  8192
#define TOP_K    10
#define PERP_W   0.01

// r28 = r26-exact + ONE finalize change (f32 x-slice).
//  - r27 POSTMORTEM: cand16 (global top-16 by bf16 key) broke correctness
//    (idx absmax 672): the bf16-key ordering vs fp64 ordering needs the
//    per-half top-16 (32 candidates) slack. Candidate structure MUST stay
//    r26's per-half cand32. gemm reverted to r18-exact.
//  - finalize: xq[16] fp64 (32 VGPR) -> xv0..3 f32 (16 VGPR), converted to
//    f64 on use inside DOT16 (exact conversion, same fma order -> bitwise
//    identical; r23-validated passing). Unlike r23, NO waves_per_eu cap, so
//    if the default 64-reg/8-wave allocator was spilling finalize's ~80
//    live values, this ducks under the threshold at FULL occupancy.
//    Also sqrt(x2)>1e-6 -> x2>1e-12 (monotone sqrt; x2 = 0 or O(10); r23
//    validated).
//  - prep/gemm/entropy/scalars: byte-identical to r26 (175.4 us, absmax 0).

// Output layout (all float32, concatenated in return order)
#define QST_OFF   0
#define LOSS_OFF  (N_ROWS * EMB_DIM)                 // 1048576
#define IDX_OFF   (LOSS_OFF + 1)                     // 1048577
#define MIND_OFF  (IDX_OFF + N_ROWS)                 // 1064961
#define PERP_OFF  (MIND_OFF + N_ROWS)                // 1081345

// ws layout (bytes)
#define WS_E2C    0                                  // 8192 f32 = 512-||e||^2/2 (32 KB)
#define WS_E2D    32768                              // 8192 f64   (64 KB)
#define WS_CBS    98304                              // swizzled bf16 codebook (1 MB)
#define WS_HIST   1146880                            // 8192 i32  (32 KB)
#define WS_LOSSP  1179648                            // 4096 f64  (32 KB)
#define WS_NVP    1212416                            // 4096 i32  (16 KB)
#define WS_C32    1228800                            // 16384*32 u16 (1 MB); hpart reuses after finalize

typedef short bf16x8 __attribute__((ext_vector_type(8)));
typedef float f32x4  __attribute__((ext_vector_type(4)));

__device__ __forceinline__ unsigned umx(unsigned a, unsigned b) {
    return __builtin_elementwise_max(a, b);
}
__device__ __forceinline__ unsigned umn(unsigned a, unsigned b) {
    return __builtin_elementwise_min(a, b);
}

__device__ __forceinline__ unsigned short f2bf(float f) {
    // round-to-nearest-even fp32 -> bf16 (inputs are finite gaussians)
    unsigned int u = __float_as_uint(f);
    unsigned int r = u + 0x7fffu + ((u >> 16) & 1u);
    return (unsigned short)(r >> 16);
}

// ---------------------------------------------------------------------------
// Kernel 0: prep — 4 threads per code (128 blocks): quad shuffle-reduce for
// ||e||^2 (fp32 + fp64), bf16 swizzled stores, zero histogram.
// ---------------------------------------------------------------------------
__global__ __launch_bounds__(256) void vq_prep(const float* __restrict__ cb,
                                               float* __restrict__ e2c,
                                               double* __restrict__ e2d,
                                               unsigned short* __restrict__ cbs,
                                               int* __restrict__ hist) {
    const int g  = blockIdx.x * 256 + threadIdx.x;   // 0..32767
    const int k  = g >> 2;                           // code 0..8191
    const int lq = g & 3;                            // dim quarter

    if (g < NUM_EMB) hist[g] = 0;

    const float4* rp = (const float4*)(cb + (size_t)k * EMB_DIM + lq * 16);
    float  s  = 0.0f;
    double sd = 0.0;
    unsigned pk[8];
#pragma unroll
    for (int i = 0; i < 4; ++i) {
        const float4 v = rp[i];
        s  += v.x * v.x + v.y * v.y + v.z * v.z + v.w * v.w;
        sd += (double)v.x * (double)v.x + (double)v.y * (double)v.y
            + (double)v.z * (double)v.z + (double)v.w * (double)v.w;
        pk[2 * i + 0] = (unsigned)f2bf(v.x) | ((unsigned)f2bf(v.y) << 16);
        pk[2 * i + 1] = (unsigned)f2bf(v.z) | ((unsigned)f2bf(v.w) << 16);
    }
    // quad reduce (xor 1,2 stays inside the quad)
    s  += __shfl_xor(s, 1);  s  += __shfl_xor(s, 2);
    sd += __shfl_xor(sd, 1); sd += __shfl_xor(sd, 2);
    if (lq == 0) { e2c[k] = 512.0f - 0.5f * s; e2d[k] = sd; }

    // swizzled store: this thread owns 2 of the code's 8 16B chunks
    const int tp = k >> 5, r32 = k & 31, rsub = r32 & 15;
    unsigned short* basep = cbs + ((size_t)tp << 11)
                          + ((unsigned)(r32 & 16) << 6)
                          + (rsub << 3);
    const int hi  = lq >> 1;          // 0 = lo half (dims 0..31), 1 = hi half
    const int q2s = (lq & 1) * 2;     // starting q2 within half
    uint4 c0, c1;
    c0.x = pk[0]; c0.y = pk[1]; c0.z = pk[2]; c0.w = pk[3];
    c1.x = pk[4]; c1.y = pk[5]; c1.z = pk[6]; c1.w = pk[7];
    *(uint4*)(basep + hi * 512 + (q2s + 0) * 128) = c0;
    *(uint4*)(basep + hi * 512 + (q2s + 1) * 128) = c1;
}

// ---------------------------------------------------------------------------
// Kernel 1: MFMA distance GEMM + per-lane register top-12 (dual-chain) +
// per-half per-row key-top-16 via ballot binary search. (r18-exact, 82.4 us)
// ---------------------------------------------------------------------------
__global__ __launch_bounds__(256) void vq_gemm_topk(
        const float* __restrict__ inp, const unsigned short* __restrict__ cbs,
        const float* __restrict__ e2c, unsigned short* __restrict__ cand32) {
    __shared__ unsigned keysh[16][193];   // [row][slot 0..191], pad 193

    const int tid   = threadIdx.x;
    const int w     = tid >> 6;        // wave chunk 0..3
    const int lane  = tid & 63;
    const int q     = lane >> 4;       // quad: k-slice for A/B, code subgroup for D
    const int rsub  = lane & 15;
    const int row0  = blockIdx.x * 16;
    const int row   = row0 + rsub;
    const int half0 = blockIdx.y * 4096;
    const int cbase = half0 + w * 1024;
    const int tpbase = cbase >> 5;     // tile-pair base index

    const int eoff = q << 2;           // e2 lane offset (floats)

    // B fragments (this lane's row, k = q*8+j and +32), fp32 -> bf16
    bf16x8 b0, b1;
    {
        const float* xp = inp + (size_t)row * EMB_DIM + q * 8;
#pragma unroll
        for (int j = 0; j < 8; ++j) b0[j] = (short)f2bf(xp[j]);
#pragma unroll
        for (int j = 0; j < 8; ++j) b1[j] = (short)f2bf(xp[32 + j]);
    }

    // two independent sorted-desc top-12 lists: la <- even tiles, lb <- odd
    unsigned la[12], lb[12];
#pragma unroll
    for (int i = 0; i < 12; ++i) { la[i] = 0u; lb[i] = 0u; }

    // fully-coalesced loads: base is wave-uniform, lane offset = lane*16B
#define LOADP(P0,P1,P2,P3,E0,E1,TT) { \
        const bf16x8* bp_ = ((const bf16x8*)cbs) + (size_t)(tpbase + (TT)) * 256; \
        P0 = bp_[lane];        P1 = bp_[lane + 64]; \
        P2 = bp_[lane + 128];  P3 = bp_[lane + 192]; \
        const float* ep_ = e2c + cbase + (TT) * 32; \
        E0 = *(const f32x4*)(ep_ + eoff); \
        E1 = *(const f32x4*)(ep_ + eoff + 16); }

    bf16x8 A00, A01, A10, A11, B00, B01, B10, B11;
    f32x4  Ae0, Ae1, Be0, Be1;
    LOADP(A00, A01, A10, A11, Ae0, Ae1, 0)
    LOADP(B00, B01, B10, B11, Be0, Be1, 1)

    // descending compare-exchange: max to first operand
#define CE(A,B) { const unsigned mx_ = umx(A, B), mn_ = umn(A, B); \
                  A = mx_; B = mn_; }

    // descending 3-sort via 3-input ops (3 instrs, depth 1)
#define SORT3(A,B,C) { const unsigned x3_ = A, y3_ = B, z3_ = C; \
        unsigned mx3_, md3_, mn3_; \
        asm("v_max3_u32 %0, %1, %2, %3" : "=v"(mx3_) : "v"(x3_), "v"(y3_), "v"(z3_)); \
        asm("v_med3_u32 %0, %1, %2, %3" : "=v"(md3_) : "v"(x3_), "v"(y3_), "v"(z3_)); \
        asm("v_min3_u32 %0, %1, %2, %3" : "=v"(mn3_) : "v"(x3_), "v"(y3_), "v"(z3_)); \
        A = mx3_; B = md3_; C = mn3_; }

    // bitonic-12 cleaner, descending (valid for any bitonic-12 input)
#define RESORT(L) { \
        CE(L[0],L[6]) CE(L[1],L[7]) CE(L[2],L[8])  CE(L[3],L[9])  CE(L[4],L[10]) CE(L[5],L[11]) \
        CE(L[0],L[3]) CE(L[1],L[4]) CE(L[2],L[5])  CE(L[6],L[9])  CE(L[7],L[10]) CE(L[8],L[11]) \
        SORT3(L[0],L[1],L[2]) SORT3(L[3],L[4],L[5]) \
        SORT3(L[6],L[7],L[8]) SORT3(L[9],L[10],L[11]) }

#define SUBITER(P0,P1,P2,P3,E0,E1,TT,TP,L) { \
        const bf16x8 c00_ = P0, c01_ = P1, c10_ = P2, c11_ = P3; \
        const f32x4  ce0_ = E0, ce1_ = E1; \
        LOADP(P0, P1, P2, P3, E0, E1, (TP) & 31) \
        f32x4 acc0_ = __builtin_amdgcn_mfma_f32_16x16x32_bf16(c00_, b0, ce0_, 0, 0, 0); \
        acc0_       = __builtin_amdgcn_mfma_f32_16x16x32_bf16(c01_, b1, acc0_, 0, 0, 0); \
        f32x4 acc1_ = __builtin_amdgcn_mfma_f32_16x16x32_bf16(c10_, b0, ce1_, 0, 0, 0); \
        acc1_       = __builtin_amdgcn_mfma_f32_16x16x32_bf16(c11_, b1, acc1_, 0, 0, 0); \
        const unsigned tb_ = (unsigned)((TT) << 3); \
        unsigned k0 = (__float_as_uint(acc0_[0]) & 0xFFFFFF00u) | (tb_ + 0u); \
        unsigned k1 = (__float_as_uint(acc0_[1]) & 0xFFFFFF00u) | (tb_ + 1u); \
        unsigned k2 = (__float_as_uint(acc0_[2]) & 0xFFFFFF00u) | (tb_ + 2u); \
        unsigned k3 = (__float_as_uint(acc0_[3]) & 0xFFFFFF00u) | (tb_ + 3u); \
        unsigned k4 = (__float_as_uint(acc1_[0]) & 0xFFFFFF00u) | (tb_ + 4u); \
        unsigned k5 = (__float_as_uint(acc1_[1]) & 0xFFFFFF00u) | (tb_ + 5u); \
        unsigned k6 = (__float_as_uint(acc1_[2]) & 0xFFFFFF00u) | (tb_ + 6u); \
        unsigned k7 = (__float_as_uint(acc1_[3]) & 0xFFFFFF00u) | (tb_ + 7u); \
        /* Batcher odd-even mergesort, 8 keys, descending (19 CE) */ \
        CE(k0,k1) CE(k2,k3) CE(k4,k5) CE(k6,k7) \
        CE(k0,k2) CE(k1,k3) CE(k4,k6) CE(k5,k7) \
        CE(k1,k2) CE(k5,k6) \
        CE(k0,k4) CE(k1,k5) CE(k2,k6) CE(k3,k7) \
        CE(k2,k4) CE(k3,k5) \
        CE(k1,k2) CE(k3,k4) CE(k5,k6) \
        /* unconditional half-cleaner merge (no-op when nothing inserts) */ \
        CE(L[11],k0) CE(L[10],k1) CE(L[9],k2) CE(L[8],k3) \
        CE(L[7],k4)  CE(L[6],k5)  CE(L[5],k6) CE(L[4],k7) \
        RESORT(L) }

    for (int t = 0; t < 32; t += 2) {
        SUBITER(A00, A01, A10, A11, Ae0, Ae1, t,     t + 2, la)
        SUBITER(B00, B01, B10, B11, Be0, Be1, t + 1, t + 3, lb)
    }
#undef SUBITER
#undef LOADP

    // recombine: top-12(la ∪ lb) sorted desc — identical multiset+order to a
    // single-list top-12 of all 256 keys.  12-wide half-cleaner, then resort.
    CE(la[11], lb[0]) CE(la[10], lb[1]) CE(la[9], lb[2])  CE(la[8], lb[3])
    CE(la[7],  lb[4]) CE(la[6],  lb[5]) CE(la[5], lb[6])  CE(la[4], lb[7])
    CE(la[3],  lb[8]) CE(la[2],  lb[9]) CE(la[1], lb[10]) CE(la[0], lb[11])
    RESORT(la)
#undef RESORT
#undef SORT3
#undef CE

    // dump keys to LDS: slot = w*48 + q*12 + k  (0..191)
    {
        unsigned* kr = &keysh[rsub][w * 48 + q * 12];
#pragma unroll
        for (int i = 0; i < 12; ++i) kr[i] = la[i];
    }
    __syncthreads();

    // per-row key-top-16 over 192 keys via ballot binary search.
    for (int rr = 0; rr < 4; ++rr) {
        const int lr = 4 * w + rr;
        const unsigned ka = keysh[lr][lane];
        const unsigned kb = keysh[lr][lane + 64];
        const unsigned kc = keysh[lr][lane + 128];

        unsigned tau = 0u;
#pragma unroll
        for (int b = 31; b >= 0; --b) {
            const unsigned t2 = tau | (1u << b);
            const int cnt = __popcll(__ballot(ka >= t2))
                          + __popcll(__ballot(kb >= t2))
                          + __popcll(__ballot(kc >= t2));
            if (cnt >= 16) tau = t2;
        }

        const unsigned long long m0 = __ballot(ka >= tau);
        const unsigned long long m1 = __ballot(kb >= tau);
        const unsigned long long m2 = __ballot(kc >= tau);
        const unsigned long long below = (lane == 0) ? 0ull
                                        : (~0ull >> (64 - lane));
        const int c0 = __popcll(m0);
        const int c1 = __popcll(m1);
        const int p0 = __popcll(m0 & below);
        const int p1 = c0 + __popcll(m1 & below);
        const int p2 = c0 + c1 + __popcll(m2 & below);

        unsigned short* outp =
            cand32 + (size_t)(row0 + lr) * 32 + blockIdx.y * 16;

#define EMIT(KX, SLOT, POS) \
        if ((KX) >= tau && (POS) < 16) { \
            const unsigned slot_ = (unsigned)(SLOT); \
            const unsigned idx_  = (KX) & 0xFFu; \
            const unsigned wq_   = slot_ / 48u; \
            const unsigned qq_   = (slot_ % 48u) / 12u; \
            const unsigned code_ = (unsigned)half0 + wq_ * 1024u \
                                 + ((idx_ >> 3) << 5) + (((idx_ >> 2) & 1u) << 4) \
                                 + (qq_ << 2) + (idx_ & 3u); \
            outp[POS] = (unsigned short)code_; \
        }
        EMIT(ka, lane,       p0)
        EMIT(kb, lane + 64,  p1)
        EMIT(kc, lane + 128, p2)
#undef EMIT
    }
}

// ---------------------------------------------------------------------------
// Kernel 2: fp64 re-rank of the 32 candidates (both gathers + e2d hoisted,
// one latency exposure), rank-based stable (d,idx) selection + Gumbel argmax,
// outputs, scattered-bin histogram atomics, per-block partial stores.
// x-slice in f32 (16 VGPR, was fp64 xq[16]=32): f64 cvt on use is exact,
// same fma order -> bitwise identical (r23-validated). Default launch
// bounds: if the 64-reg/8-wave target was spilling, -16 live regs ducks
// under the threshold WITHOUT an occupancy cap.
// ---------------------------------------------------------------------------
__global__ __launch_bounds__(256) void vq_finalize(const float* __restrict__ inp,
                                                   const float* __restrict__ cb,
                                                   const double* __restrict__ e2d,
                                                   const float* __restrict__ gumbel,
                                                   const unsigned short* __restrict__ cand32,
                                                   float* __restrict__ out,
                                                   int* __restrict__ hist,
                                                   double* __restrict__ lossp,
                                                   int* __restrict__ nvp) {
    __shared__ double dvs[4][32];
    __shared__ int    dis[4][32];
    __shared__ double wl[4];
    __shared__ int    wv[4];

    const int tid  = threadIdx.x;
    const int w    = tid >> 6;
    const int lane = tid & 63;
    const int row  = blockIdx.x * 4 + w;
    const int g    = lane >> 2;   // quad id 0..15
    const int lq   = lane & 3;    // quarter within quad

    const float xf = inp[(size_t)row * EMB_DIM + lane];
    const double xd = (double)xf;

    // hoisted candidate ids + gathers + e2d (one latency exposure)
    const int code0 = (int)cand32[(size_t)row * 32 + g];
    const int code1 = (int)cand32[(size_t)row * 32 + 16 + g];
    const float4* ep0 = (const float4*)(cb + ((size_t)code0 << 6) + (lq << 4));
    const float4* ep1 = (const float4*)(cb + ((size_t)code1 << 6) + (lq << 4));
    const float4 a0 = ep0[0], a1 = ep0[1], a2 = ep0[2], a3 = ep0[3];
    const float4 b0 = ep1[0], b1 = ep1[1], b2 = ep1[2], b3 = ep1[3];
    const double ed0 = e2d[code0];
    const double ed1 = e2d[code1];

    // wave-wide ||x||^2 in fp64
    double x2 = xd * xd;
#pragma unroll
    for (int off = 32; off >= 1; off >>= 1) x2 += __shfl_xor(x2, off);
    // sqrt(x2) > 1e-6  <=>  x2 > 1e-12 (sqrt monotone; x2 = 0 or O(10));
    // avoids the fp64 sqrt sequence (r23-validated).
    const bool valid = x2 > 1e-12;

    // lane's x-slice: dims [lq*16, lq*16+16) in f32 registers (16 VGPRs);
    // converted to f64 on use (exact).
    const float4* xp = (const float4*)(inp + (size_t)row * EMB_DIM + (lq << 4));
    const float4 xv0 = xp[0], xv1 = xp[1], xv2 = xp[2], xv3 = xp[3];

#define DOT16(V0,V1,V2,V3, EDV, J, CODE) { \
        double d0_ = 0.0, d1_ = 0.0; \
        d0_ = fma((double)xv0.x, (double)V0.x, d0_);  d0_ = fma((double)xv0.y, (double)V0.y, d0_); \
        d0_ = fma((double)xv0.z, (double)V0.z, d0_);  d0_ = fma((double)xv0.w, (double)V0.w, d0_); \
        d0_ = fma((double)xv1.x, (double)V1.x, d0_);  d0_ = fma((double)xv1.y, (double)V1.y, d0_); \
        d0_ = fma((double)xv1.z, (double)V1.z, d0_);  d0_ = fma((double)xv1.w, (double)V1.w, d0_); \
        d1_ = fma((double)xv2.x, (double)V2.x, d1_);  d1_ = fma((double)xv2.y, (double)V2.y, d1_); \
        d1_ = fma((double)xv2.z, (double)V2.z, d1_);  d1_ = fma((double)xv2.w, (double)V2.w, d1_); \
        d1_ = fma((double)xv3.x, (double)V3.x, d1_);  d1_ = fma((double)xv3.y, (double)V3.y, d1_); \
        d1_ = fma((double)xv3.z, (double)V3.z, d1_);  d1_ = fma((double)xv3.w, (double)V3.w, d1_); \
        double dot_ = d0_ + d1_; \
        dot_ += __shfl_xor(dot_, 1); \
        dot_ += __shfl_xor(dot_, 2); \
        if (lq == 0) { \
            dvs[w][J] = x2 + (EDV) - 2.0 * dot_; \
            dis[w][J] = (CODE); \
        } }

    DOT16(a0, a1, a2, a3, ed0, g,      code0)
    DOT16(b0, b1, b2, b3, ed1, 16 + g, code1)
#undef DOT16
    __syncthreads();

    // one candidate per lane (lane<32). Rank by (d, idx) — exact stable order.
    const bool has = (lane < 32);
    double cd = has ? dvs[w][lane] : 1.0e300;
    int    ci = has ? dis[w][lane] : 0x7fffffff;

    int rank = 0;
#pragma unroll
    for (int off = 1; off < 32; ++off) {
        const double od = __shfl_xor(cd, off);   // stays within 0..31 group
        const int    oi = __shfl_xor(ci, off);
        if (od < cd || (od == cd && oi < ci)) ++rank;
    }

    // lanes with rank<10 (and holding a candidate) join the Gumbel race
    float sc = -3.0e38f;
    if (has && rank < TOP_K)
        sc = (float)(-cd) + gumbel[(size_t)row * TOP_K + rank];

    // wave argmax of (sc, tie -> smaller rank) carrying (cd, ci)
    double bd = cd; int bi = ci; int brk = rank;
#pragma unroll
    for (int off = 1; off < 64; off <<= 1) {
        const float  os = __shfl_xor(sc, off);
        const double od = __shfl_xor(bd, off);
        const int    oi = __shfl_xor(bi, off);
        const int    ork = __shfl_xor(brk, off);
        if (os > sc || (os == sc && ork < brk)) {
            sc = os; bd = od; bi = oi; brk = ork;
        }
    }
    const int   cidx = bi;            // uniform across wave
    const float mind = (float)bd;

    const float vm = valid ? 1.0f : 0.0f;
    const float qv = cb[(size_t)cidx * EMB_DIM + lane];
    out[QST_OFF + (size_t)row * EMB_DIM + lane] = xf + (qv * vm - xf);

    // loss term uses UNMASKED q_valid, masked by vm
    const double dq = (double)qv - xd;
    double l = dq * dq * (double)vm;
#pragma unroll
    for (int off = 32; off >= 1; off >>= 1) l += __shfl_xor(l, off);

    if (lane == 0) {
        wl[w] = l;
        wv[w] = valid ? 1 : 0;
        if (valid) atomicAdd(&hist[cidx], 1);   // scattered bins, low contention
        out[IDX_OFF + row]  = valid ? (float)cidx : 0.0f;
        out[MIND_OFF + row] = valid ? mind : 0.0f;
    }
    __syncthreads();
    if (tid == 0) {
        lossp[blockIdx.x] = wl[0] + wl[1] + wl[2] + wl[3];
        nvp[blockIdx.x]   = wv[0] + wv[1] + wv[2] + wv[3];
    }
}

// ---------------------------------------------------------------------------
// Kernel 3a: entropy partials — 8 blocks x 1024 threads, one bin per thread.
// ---------------------------------------------------------------------------
__global__ __launch_bounds__(1024) void vq_entropy(const int* __restrict__ nvp,
                                                   const int* __restrict__ hist,
                                                   double* __restrict__ hpart) {
    __shared__ int    redi[1024];
    __shared__ double red[1024];
    const int tid = threadIdx.x;

    // nv: integer sum of 4096 per-block valid counts (order-independent)
    int nvl = 0;
#pragma unroll
    for (int i = 0; i < 4; ++i) nvl += nvp[tid + 1024 * i];
    redi[tid] = nvl;
    __syncthreads();
    for (int s = 512; s >= 1; s >>= 1) {
        if (tid < s) redi[tid] += redi[tid + s];
        __syncthreads();
    }
    const double nv = (redi[0] > 0) ? (double)redi[0] : 1.0;

    // this thread's bin term
    const int k = blockIdx.x * 1024 + tid;
    const double p = (double)hist[k] / nv;
    red[tid] = p * log(p + 1e-10);
    __syncthreads();
    for (int s = 512; s >= 1; s >>= 1) {
        if (tid < s) red[tid] += red[tid + s];
        __syncthreads();
    }
    if (tid == 0) hpart[blockIdx.x] = red[0];
}

// ---------------------------------------------------------------------------
// Kernel 3b: reduce per-block partials -> scalars. Single block, 1024 threads.
// ---------------------------------------------------------------------------
__global__ __launch_bounds__(1024) void vq_scalars(const double* __restrict__ lossp,
                                                   const int* __restrict__ nvp,
                                                   const double* __restrict__ hpart,
                                                   float* __restrict__ out) {
    __shared__ double red[1024];
    __shared__ double s_nv;
    const int tid = threadIdx.x;

    double lsum = 0.0;
    int    nvl  = 0;
#pragma unroll
    for (int i = 0; i < 4; ++i) {
        const int j = tid + 1024 * i;   // 4096 partials
        lsum += lossp[j];
        nvl  += nvp[j];
    }

    red[tid] = lsum;
    __syncthreads();
    for (int s = 512; s >= 1; s >>= 1) {
        if (tid < s) red[tid] += red[tid + s];
        __syncthreads();
    }
    const double losstot = red[0];
    __syncthreads();

    red[tid] = (double)nvl;
    __syncthreads();
    for (int s = 512; s >= 1; s >>= 1) {
        if (tid < s) red[tid] += red[tid + s];
        __syncthreads();
    }
    if (tid == 0) s_nv = (red[0] > 0.5) ? red[0] : 1.0;
    __syncthreads();
    const double nv = s_nv;

    if (tid == 0) {
        double H = 0.0;
#pragma unroll
        for (int b = 0; b < 8; ++b) H += hpart[b];
        const double perp = exp(-H);
        const double ploss = -log(perp + 1e-10);
        const double lvq = losstot / (nv * (double)EMB_DIM);
        out[LOSS_OFF] = (float)(lvq + PERP_W * ploss);
        out[PERP_OFF] = (float)perp;
    }
}

// ---------------------------------------------------------------------------
extern "C" void kernel_launch(void* const* d_in, const int* in_sizes, int n_in,
                              void* d_out, int out_size, void* d_ws, size_t ws_size,
                              hipStream_t stream) {
    const float* inp    = (const float*)d_in[0];  // [16384, 64]
    const float* cb     = (const float*)d_in[1];  // [8192, 64]
    const float* gumbel = (const float*)d_in[2];  // [16384, 10]
    float* out = (float*)d_out;

    char* ws = (char*)d_ws;
    float*          e2c    = (float*)(ws + WS_E2C);
    double*         e2d    = (double*)(ws + WS_E2D);
    unsigned short* cbs    = (unsigned short*)(ws + WS_CBS);
    int*            hist   = (int*)(ws + WS_HIST);
    double*         lossp  = (double*)(ws + WS_LOSSP);
    int*            nvp    = (int*)(ws + WS_NVP);
    unsigned short* cand32 = (unsigned short*)(ws + WS_C32);
    double*         hpart  = (double*)(ws + WS_C32);  // reuses cand32 (dead after finalize)

    vq_prep<<<NUM_EMB * 4 / 256, 256, 0, stream>>>(cb, e2c, e2d, cbs, hist);
    vq_gemm_topk<<<dim3(N_ROWS / 16, 2), 256, 0, stream>>>(inp, cbs, e2c, cand32);
    vq_finalize<<<N_ROWS / 4, 256, 0, stream>>>(inp, cb, e2d, gumbel, cand32, out,
                                                hist, lossp, nvp);
    vq_entropy<<<8, 1024, 0, stream>>>(nvp, hist, hpart);
    vq_scalars<<<1, 1024, 0, stream>>>(lossp, nvp, hpart, out);
}